// Round 1
// baseline (87.522 us; speedup 1.0000x reference)
//
#include <hip/hip_runtime.h>
#include <math.h>

#define NPIX 65536          // 256*256 pixels per instance
#define NGROUPS 64
#define DICE_EPS 1e-5f

// ---------------------------------------------------------------------------
// Kernel 1: per-teacher-instance dice reductions.
// One block per teacher instance; computes inter = sum(x*t), xx = sum(x*x),
// tt = sum(t*t); writes iou_loss[i] and xx_T[i] (reused by kernel 3).
// ---------------------------------------------------------------------------
__global__ __launch_bounds__(256) void teacher_dice_kernel(
    const float* __restrict__ preds_T, const float* __restrict__ gt_T,
    float* __restrict__ iou_loss, float* __restrict__ xx_T) {
  const int i = blockIdx.x;
  const float4* __restrict__ x = (const float4*)(preds_T + (size_t)i * NPIX);
  const float4* __restrict__ t = (const float4*)(gt_T + (size_t)i * NPIX);

  float inter = 0.f, xx = 0.f, tt = 0.f;
  for (int k = threadIdx.x; k < NPIX / 4; k += 256) {
    float4 a = x[k];
    float4 b = t[k];
    inter += a.x * b.x + a.y * b.y + a.z * b.z + a.w * b.w;
    xx    += a.x * a.x + a.y * a.y + a.z * a.z + a.w * a.w;
    tt    += b.x * b.x + b.y * b.y + b.z * b.z + b.w * b.w;
  }
  // wave (64-lane) butterfly reduce for all three sums
  for (int off = 32; off > 0; off >>= 1) {
    inter += __shfl_down(inter, off);
    xx    += __shfl_down(xx, off);
    tt    += __shfl_down(tt, off);
  }
  __shared__ float s[3][4];
  const int wave = threadIdx.x >> 6, lane = threadIdx.x & 63;
  if (lane == 0) { s[0][wave] = inter; s[1][wave] = xx; s[2][wave] = tt; }
  __syncthreads();
  if (threadIdx.x == 0) {
    float I = 0.f, X = 0.f, T = 0.f;
    for (int w = 0; w < 4; ++w) { I += s[0][w]; X += s[1][w]; T += s[2][w]; }
    iou_loss[i] = 1.f - 2.f * I / (X + T + DICE_EPS);
    xx_T[i] = X;
  }
}

// ---------------------------------------------------------------------------
// Kernel 2: per-group argmin (first-min semantics, matching jnp.argmin) and
// presence flags. Single wave. Also zeroes the scalar output.
// ---------------------------------------------------------------------------
__global__ void nms_kernel(const float* __restrict__ iou_loss,
                           const int* __restrict__ gt_inds_T, int nT,
                           int* __restrict__ best_idx,
                           int* __restrict__ present,
                           float* __restrict__ out) {
  const int g = threadIdx.x;
  if (g == 0) *out = 0.f;
  if (g < NGROUPS) {
    float bv = INFINITY;
    int bi = 0, pres = 0;
    for (int i = 0; i < nT; ++i) {
      if (gt_inds_T[i] == g) {
        pres = 1;
        float v = iou_loss[i];
        if (v < bv) { bv = v; bi = i; }   // strict < keeps FIRST min index
      }
    }
    best_idx[g] = bi;
    present[g] = pres;
  }
}

// ---------------------------------------------------------------------------
// Kernel 3: per-student dice vs matched teacher mask; masked atomic sum.
// Reuses xx_T[j] for sum(t*t). One block per student instance.
// ---------------------------------------------------------------------------
__global__ __launch_bounds__(256) void student_dice_kernel(
    const float* __restrict__ preds_S, const float* __restrict__ preds_T,
    const float* __restrict__ xx_T, const int* __restrict__ gt_inds_S,
    const int* __restrict__ best_idx, const int* __restrict__ present,
    float* __restrict__ out) {
  const int s = blockIdx.x;
  const int g = gt_inds_S[s];
  if (!present[g]) return;   // invalid pair contributes nothing
  const int j = best_idx[g];

  const float4* __restrict__ x = (const float4*)(preds_S + (size_t)s * NPIX);
  const float4* __restrict__ t = (const float4*)(preds_T + (size_t)j * NPIX);

  float inter = 0.f, xx = 0.f;
  for (int k = threadIdx.x; k < NPIX / 4; k += 256) {
    float4 a = x[k];
    float4 b = t[k];
    inter += a.x * b.x + a.y * b.y + a.z * b.z + a.w * b.w;
    xx    += a.x * a.x + a.y * a.y + a.z * a.z + a.w * a.w;
  }
  for (int off = 32; off > 0; off >>= 1) {
    inter += __shfl_down(inter, off);
    xx    += __shfl_down(xx, off);
  }
  __shared__ float s2[2][4];
  const int wave = threadIdx.x >> 6, lane = threadIdx.x & 63;
  if (lane == 0) { s2[0][wave] = inter; s2[1][wave] = xx; }
  __syncthreads();
  if (threadIdx.x == 0) {
    float I = 0.f, X = 0.f;
    for (int w = 0; w < 4; ++w) { I += s2[0][w]; X += s2[1][w]; }
    float per_pair = 1.f - 2.f * I / (X + xx_T[j] + DICE_EPS);
    atomicAdd(out, per_pair);
  }
}

extern "C" void kernel_launch(void* const* d_in, const int* in_sizes, int n_in,
                              void* d_out, int out_size, void* d_ws, size_t ws_size,
                              hipStream_t stream) {
  const float* preds_T   = (const float*)d_in[0];
  const float* preds_S   = (const float*)d_in[1];
  // d_in[2] = im_ind (unused)
  const float* gt_T      = (const float*)d_in[3];
  // d_in[4] = gt_S (unused), d_in[5] = iter (unused)
  const int* gt_inds_T   = (const int*)d_in[6];
  const int* gt_inds_S   = (const int*)d_in[7];
  float* out = (float*)d_out;

  const int nT = in_sizes[6];   // 256
  const int nS = in_sizes[7];   // 128

  // workspace layout
  float* iou_loss = (float*)d_ws;            // nT floats
  float* xx_T     = iou_loss + nT;           // nT floats
  int*   best_idx = (int*)(xx_T + nT);       // NGROUPS ints
  int*   present  = best_idx + NGROUPS;      // NGROUPS ints

  teacher_dice_kernel<<<nT, 256, 0, stream>>>(preds_T, gt_T, iou_loss, xx_T);
  nms_kernel<<<1, 64, 0, stream>>>(iou_loss, gt_inds_T, nT, best_idx, present, out);
  student_dice_kernel<<<nS, 256, 0, stream>>>(preds_S, preds_T, xx_T, gt_inds_S,
                                              best_idx, present, out);
}

// Round 2
// 72.360 us; speedup vs baseline: 1.2095x; 1.2095x over previous
//
#include <hip/hip_runtime.h>
#include <math.h>

#define NPIX 65536          // 256*256 pixels per instance
#define NGROUPS 64
#define DICE_EPS 1e-5f
#define SPLIT_T 8           // blocks per teacher instance
#define SPLIT_S 16          // blocks per student instance
#define MAX_NT 256

// ---------------------------------------------------------------------------
// Kernel 1: teacher partial reductions. Grid = nT*SPLIT_T blocks; block b
// handles a contiguous 1/SPLIT_T slice of instance b/SPLIT_T. Partials are
// atomically accumulated into acc_T[i*3 + {inter, xx, tt}].
// ---------------------------------------------------------------------------
__global__ __launch_bounds__(256) void teacher_partial(
    const float* __restrict__ preds_T, const float* __restrict__ gt_T,
    float* __restrict__ acc_T) {
  const int i = blockIdx.x / SPLIT_T;
  const int c = blockIdx.x % SPLIT_T;
  const size_t base = (size_t)i * NPIX + (size_t)c * (NPIX / SPLIT_T);
  const float4* __restrict__ x = (const float4*)(preds_T + base);
  const float4* __restrict__ t = (const float4*)(gt_T + base);

  float inter = 0.f, xx = 0.f, tt = 0.f;
  const int n4 = NPIX / SPLIT_T / 4;        // 2048 float4s per block
  for (int k = threadIdx.x; k < n4; k += 256) {
    float4 a = x[k];
    float4 b = t[k];
    inter += a.x * b.x + a.y * b.y + a.z * b.z + a.w * b.w;
    xx    += a.x * a.x + a.y * a.y + a.z * a.z + a.w * a.w;
    tt    += b.x * b.x + b.y * b.y + b.z * b.z + b.w * b.w;
  }
  for (int off = 32; off > 0; off >>= 1) {
    inter += __shfl_down(inter, off);
    xx    += __shfl_down(xx, off);
    tt    += __shfl_down(tt, off);
  }
  __shared__ float s[3][4];
  const int wave = threadIdx.x >> 6, lane = threadIdx.x & 63;
  if (lane == 0) { s[0][wave] = inter; s[1][wave] = xx; s[2][wave] = tt; }
  __syncthreads();
  if (threadIdx.x == 0) {
    float I = 0.f, X = 0.f, T = 0.f;
    for (int w = 0; w < 4; ++w) { I += s[0][w]; X += s[1][w]; T += s[2][w]; }
    atomicAdd(&acc_T[i * 3 + 0], I);
    atomicAdd(&acc_T[i * 3 + 1], X);
    atomicAdd(&acc_T[i * 3 + 2], T);
  }
}

// ---------------------------------------------------------------------------
// Kernel 2: finalize teacher dice + per-group argmin (first-min semantics,
// matching jnp.argmin). One block, 256 threads; iou_loss lives in LDS only.
// ---------------------------------------------------------------------------
__global__ __launch_bounds__(256) void finalize_nms(
    const float* __restrict__ acc_T, const int* __restrict__ gt_inds_T, int nT,
    float* __restrict__ xx_T, int* __restrict__ best_idx,
    int* __restrict__ present) {
  __shared__ float iou[MAX_NT];
  const int i = threadIdx.x;
  if (i < nT) {
    float I = acc_T[i * 3 + 0], X = acc_T[i * 3 + 1], T = acc_T[i * 3 + 2];
    iou[i] = 1.f - 2.f * I / (X + T + DICE_EPS);
    xx_T[i] = X;
  }
  __syncthreads();
  if (i < NGROUPS) {
    float bv = INFINITY;
    int bi = 0, pres = 0;
    for (int k = 0; k < nT; ++k) {
      if (gt_inds_T[k] == i) {
        pres = 1;
        float v = iou[k];
        if (v < bv) { bv = v; bi = k; }   // strict < keeps FIRST min index
      }
    }
    best_idx[i] = bi;
    present[i] = pres;
  }
}

// ---------------------------------------------------------------------------
// Kernel 3: student partial reductions vs matched teacher row.
// Grid = nS*SPLIT_S blocks; invalid students exit immediately.
// ---------------------------------------------------------------------------
__global__ __launch_bounds__(256) void student_partial(
    const float* __restrict__ preds_S, const float* __restrict__ preds_T,
    const int* __restrict__ gt_inds_S, const int* __restrict__ best_idx,
    const int* __restrict__ present, float* __restrict__ acc_S) {
  const int s = blockIdx.x / SPLIT_S;
  const int c = blockIdx.x % SPLIT_S;
  const int g = gt_inds_S[s];
  if (!present[g]) return;
  const int j = best_idx[g];

  const size_t off_s = (size_t)s * NPIX + (size_t)c * (NPIX / SPLIT_S);
  const size_t off_t = (size_t)j * NPIX + (size_t)c * (NPIX / SPLIT_S);
  const float4* __restrict__ x = (const float4*)(preds_S + off_s);
  const float4* __restrict__ t = (const float4*)(preds_T + off_t);

  float inter = 0.f, xx = 0.f;
  const int n4 = NPIX / SPLIT_S / 4;        // 1024 float4s per block
  for (int k = threadIdx.x; k < n4; k += 256) {
    float4 a = x[k];
    float4 b = t[k];
    inter += a.x * b.x + a.y * b.y + a.z * b.z + a.w * b.w;
    xx    += a.x * a.x + a.y * a.y + a.z * a.z + a.w * a.w;
  }
  for (int off = 32; off > 0; off >>= 1) {
    inter += __shfl_down(inter, off);
    xx    += __shfl_down(xx, off);
  }
  __shared__ float s2[2][4];
  const int wave = threadIdx.x >> 6, lane = threadIdx.x & 63;
  if (lane == 0) { s2[0][wave] = inter; s2[1][wave] = xx; }
  __syncthreads();
  if (threadIdx.x == 0) {
    float I = 0.f, X = 0.f;
    for (int w = 0; w < 4; ++w) { I += s2[0][w]; X += s2[1][w]; }
    atomicAdd(&acc_S[s * 2 + 0], I);
    atomicAdd(&acc_S[s * 2 + 1], X);
  }
}

// ---------------------------------------------------------------------------
// Kernel 4: final masked sum over students -> single scalar (direct write,
// so d_out never needs pre-zeroing).
// ---------------------------------------------------------------------------
__global__ __launch_bounds__(128) void student_final(
    const float* __restrict__ acc_S, const float* __restrict__ xx_T,
    const int* __restrict__ gt_inds_S, const int* __restrict__ best_idx,
    const int* __restrict__ present, float* __restrict__ out, int nS) {
  float v = 0.f;
  const int s = threadIdx.x;   // 128 threads, one per student
  if (s < nS) {
    const int g = gt_inds_S[s];
    if (present[g]) {
      const int j = best_idx[g];
      float I = acc_S[s * 2 + 0], X = acc_S[s * 2 + 1];
      v = 1.f - 2.f * I / (X + xx_T[j] + DICE_EPS);
    }
  }
  for (int off = 32; off > 0; off >>= 1) v += __shfl_down(v, off);
  __shared__ float p[2];
  if ((threadIdx.x & 63) == 0) p[threadIdx.x >> 6] = v;
  __syncthreads();
  if (threadIdx.x == 0) *out = p[0] + p[1];
}

extern "C" void kernel_launch(void* const* d_in, const int* in_sizes, int n_in,
                              void* d_out, int out_size, void* d_ws, size_t ws_size,
                              hipStream_t stream) {
  const float* preds_T = (const float*)d_in[0];
  const float* preds_S = (const float*)d_in[1];
  // d_in[2] = im_ind (unused), d_in[3] = gt_T, d_in[4] = gt_S (unused),
  // d_in[5] = iter (unused)
  const float* gt_T    = (const float*)d_in[3];
  const int* gt_inds_T = (const int*)d_in[6];
  const int* gt_inds_S = (const int*)d_in[7];
  float* out = (float*)d_out;

  const int nT = in_sizes[6];   // 256
  const int nS = in_sizes[7];   // 128

  // workspace layout (floats): acc_T[nT*3] | acc_S[nS*2] | xx_T[nT] | ints
  float* acc_T   = (float*)d_ws;
  float* acc_S   = acc_T + (size_t)nT * 3;
  float* xx_T    = acc_S + (size_t)nS * 2;
  int*   best_idx = (int*)(xx_T + nT);
  int*   present  = best_idx + NGROUPS;

  // zero only the atomic accumulators (deterministic per call)
  hipMemsetAsync(d_ws, 0, ((size_t)nT * 3 + (size_t)nS * 2) * sizeof(float),
                 stream);

  teacher_partial<<<nT * SPLIT_T, 256, 0, stream>>>(preds_T, gt_T, acc_T);
  finalize_nms<<<1, 256, 0, stream>>>(acc_T, gt_inds_T, nT, xx_T, best_idx,
                                      present);
  student_partial<<<nS * SPLIT_S, 256, 0, stream>>>(preds_S, preds_T,
                                                    gt_inds_S, best_idx,
                                                    present, acc_S);
  student_final<<<1, 128, 0, stream>>>(acc_S, xx_T, gt_inds_S, best_idx,
                                       present, out, nS);
}

// Round 3
// 71.014 us; speedup vs baseline: 1.2325x; 1.0190x over previous
//
#include <hip/hip_runtime.h>
#include <math.h>

#define NPIX 65536          // 256*256 pixels per instance
#define NGROUPS 64
#define DICE_EPS 1e-5f
#define SPLIT_T 8           // blocks per teacher/student instance (phase 1)
#define SPLIT_S 16          // blocks per student instance (cross phase)
#define MAX_NT 256

// ---------------------------------------------------------------------------
// Kernel 1 (fused streaming phase): grid = nT*SPLIT_T + nS*SPLIT_T blocks.
// First nT*SPLIT_T blocks: teacher inter/xx/tt partials.
// Remaining nS*SPLIT_T blocks: student self-dot (sum s*s) partials.
// Per-thread 8 float4 per stream, loaded in 2 unrolled batches of 4 through
// register arrays -> 8+ loads in flight per wave (ILP for latency hiding).
// ---------------------------------------------------------------------------
__global__ __launch_bounds__(256) void stream_partials(
    const float* __restrict__ preds_T, const float* __restrict__ gt_T,
    const float* __restrict__ preds_S, int nT,
    float* __restrict__ acc_T, float* __restrict__ acc_S) {
  const int tid = threadIdx.x;
  const int tBlocks = nT * SPLIT_T;
  __shared__ float sm[3][4];
  const int wave = tid >> 6, lane = tid & 63;

  if ((int)blockIdx.x < tBlocks) {
    const int i = blockIdx.x / SPLIT_T;
    const int c = blockIdx.x % SPLIT_T;
    const size_t base = (size_t)i * NPIX + (size_t)c * (NPIX / SPLIT_T);
    const float4* __restrict__ x = (const float4*)(preds_T + base);
    const float4* __restrict__ t = (const float4*)(gt_T + base);

    float inter = 0.f, xx = 0.f, tt = 0.f;
    float4 a[4], b[4];
#pragma unroll
    for (int h = 0; h < 2; ++h) {
      const int o = h * 1024 + tid;
#pragma unroll
      for (int u = 0; u < 4; ++u) a[u] = x[o + u * 256];
#pragma unroll
      for (int u = 0; u < 4; ++u) b[u] = t[o + u * 256];
#pragma unroll
      for (int u = 0; u < 4; ++u) {
        inter += a[u].x * b[u].x + a[u].y * b[u].y + a[u].z * b[u].z + a[u].w * b[u].w;
        xx    += a[u].x * a[u].x + a[u].y * a[u].y + a[u].z * a[u].z + a[u].w * a[u].w;
        tt    += b[u].x * b[u].x + b[u].y * b[u].y + b[u].z * b[u].z + b[u].w * b[u].w;
      }
    }
    for (int off = 32; off > 0; off >>= 1) {
      inter += __shfl_down(inter, off);
      xx    += __shfl_down(xx, off);
      tt    += __shfl_down(tt, off);
    }
    if (lane == 0) { sm[0][wave] = inter; sm[1][wave] = xx; sm[2][wave] = tt; }
    __syncthreads();
    if (tid == 0) {
      float I = 0.f, X = 0.f, T = 0.f;
      for (int w = 0; w < 4; ++w) { I += sm[0][w]; X += sm[1][w]; T += sm[2][w]; }
      atomicAdd(&acc_T[i * 3 + 0], I);
      atomicAdd(&acc_T[i * 3 + 1], X);
      atomicAdd(&acc_T[i * 3 + 2], T);
    }
  } else {
    const int sb = blockIdx.x - tBlocks;
    const int s = sb / SPLIT_T;
    const int c = sb % SPLIT_T;
    const size_t base = (size_t)s * NPIX + (size_t)c * (NPIX / SPLIT_T);
    const float4* __restrict__ x = (const float4*)(preds_S + base);

    float xx = 0.f;
    float4 a[4];
#pragma unroll
    for (int h = 0; h < 2; ++h) {
      const int o = h * 1024 + tid;
#pragma unroll
      for (int u = 0; u < 4; ++u) a[u] = x[o + u * 256];
#pragma unroll
      for (int u = 0; u < 4; ++u)
        xx += a[u].x * a[u].x + a[u].y * a[u].y + a[u].z * a[u].z + a[u].w * a[u].w;
    }
    for (int off = 32; off > 0; off >>= 1) xx += __shfl_down(xx, off);
    if (lane == 0) sm[0][wave] = xx;
    __syncthreads();
    if (tid == 0) {
      float X = 0.f;
      for (int w = 0; w < 4; ++w) X += sm[0][w];
      atomicAdd(&acc_S[s * 2 + 1], X);
    }
  }
}

// ---------------------------------------------------------------------------
// Kernel 2: finalize teacher dice + per-group argmin (first-min semantics,
// matching jnp.argmin). One block; gt_inds_T staged in LDS.
// ---------------------------------------------------------------------------
__global__ __launch_bounds__(256) void finalize_nms(
    const float* __restrict__ acc_T, const int* __restrict__ gt_inds_T, int nT,
    float* __restrict__ xx_T, int* __restrict__ best_idx,
    int* __restrict__ present) {
  __shared__ float iou[MAX_NT];
  __shared__ int ginds[MAX_NT];
  const int i = threadIdx.x;
  if (i < nT) {
    float I = acc_T[i * 3 + 0], X = acc_T[i * 3 + 1], T = acc_T[i * 3 + 2];
    iou[i] = 1.f - 2.f * I / (X + T + DICE_EPS);
    ginds[i] = gt_inds_T[i];
    xx_T[i] = X;
  }
  __syncthreads();
  if (i < NGROUPS) {
    float bv = INFINITY;
    int bi = 0, pres = 0;
    for (int k = 0; k < nT; ++k) {
      if (ginds[k] == i) {
        pres = 1;
        float v = iou[k];
        if (v < bv) { bv = v; bi = k; }   // strict < keeps FIRST min index
      }
    }
    best_idx[i] = bi;
    present[i] = pres;
  }
}

// ---------------------------------------------------------------------------
// Kernel 3: cross terms only — per student, sum s * matched_t. Mostly
// L3-resident reads after kernel 1. Grid = nS*SPLIT_S blocks.
// ---------------------------------------------------------------------------
__global__ __launch_bounds__(256) void cross_partial(
    const float* __restrict__ preds_S, const float* __restrict__ preds_T,
    const int* __restrict__ gt_inds_S, const int* __restrict__ best_idx,
    const int* __restrict__ present, float* __restrict__ acc_S) {
  const int s = blockIdx.x / SPLIT_S;
  const int c = blockIdx.x % SPLIT_S;
  const int g = gt_inds_S[s];
  if (!present[g]) return;
  const int j = best_idx[g];

  const size_t off_s = (size_t)s * NPIX + (size_t)c * (NPIX / SPLIT_S);
  const size_t off_t = (size_t)j * NPIX + (size_t)c * (NPIX / SPLIT_S);
  const float4* __restrict__ x = (const float4*)(preds_S + off_s);
  const float4* __restrict__ t = (const float4*)(preds_T + off_t);

  float inter = 0.f;
  float4 a[4], b[4];
  const int tid = threadIdx.x;
#pragma unroll
  for (int u = 0; u < 4; ++u) a[u] = x[tid + u * 256];
#pragma unroll
  for (int u = 0; u < 4; ++u) b[u] = t[tid + u * 256];
#pragma unroll
  for (int u = 0; u < 4; ++u)
    inter += a[u].x * b[u].x + a[u].y * b[u].y + a[u].z * b[u].z + a[u].w * b[u].w;

  for (int off = 32; off > 0; off >>= 1) inter += __shfl_down(inter, off);
  __shared__ float sm[4];
  if ((tid & 63) == 0) sm[tid >> 6] = inter;
  __syncthreads();
  if (tid == 0) {
    float I = sm[0] + sm[1] + sm[2] + sm[3];
    atomicAdd(&acc_S[s * 2 + 0], I);
  }
}

// ---------------------------------------------------------------------------
// Kernel 4: final masked sum over students -> scalar (direct write).
// ---------------------------------------------------------------------------
__global__ __launch_bounds__(128) void student_final(
    const float* __restrict__ acc_S, const float* __restrict__ xx_T,
    const int* __restrict__ gt_inds_S, const int* __restrict__ best_idx,
    const int* __restrict__ present, float* __restrict__ out, int nS) {
  float v = 0.f;
  const int s = threadIdx.x;   // 128 threads, one per student
  if (s < nS) {
    const int g = gt_inds_S[s];
    if (present[g]) {
      const int j = best_idx[g];
      float I = acc_S[s * 2 + 0], X = acc_S[s * 2 + 1];
      v = 1.f - 2.f * I / (X + xx_T[j] + DICE_EPS);
    }
  }
  for (int off = 32; off > 0; off >>= 1) v += __shfl_down(v, off);
  __shared__ float p[2];
  if ((threadIdx.x & 63) == 0) p[threadIdx.x >> 6] = v;
  __syncthreads();
  if (threadIdx.x == 0) *out = p[0] + p[1];
}

extern "C" void kernel_launch(void* const* d_in, const int* in_sizes, int n_in,
                              void* d_out, int out_size, void* d_ws, size_t ws_size,
                              hipStream_t stream) {
  const float* preds_T = (const float*)d_in[0];
  const float* preds_S = (const float*)d_in[1];
  const float* gt_T    = (const float*)d_in[3];
  // d_in[2]=im_ind, d_in[4]=gt_S, d_in[5]=iter: unused by the reference
  const int* gt_inds_T = (const int*)d_in[6];
  const int* gt_inds_S = (const int*)d_in[7];
  float* out = (float*)d_out;

  const int nT = in_sizes[6];   // 256
  const int nS = in_sizes[7];   // 128

  // workspace layout (floats): acc_T[nT*3] | acc_S[nS*2] | xx_T[nT] | ints
  float* acc_T    = (float*)d_ws;
  float* acc_S    = acc_T + (size_t)nT * 3;
  float* xx_T     = acc_S + (size_t)nS * 2;
  int*   best_idx = (int*)(xx_T + nT);
  int*   present  = best_idx + NGROUPS;

  hipMemsetAsync(d_ws, 0, ((size_t)nT * 3 + (size_t)nS * 2) * sizeof(float),
                 stream);

  stream_partials<<<nT * SPLIT_T + nS * SPLIT_T, 256, 0, stream>>>(
      preds_T, gt_T, preds_S, nT, acc_T, acc_S);
  finalize_nms<<<1, 256, 0, stream>>>(acc_T, gt_inds_T, nT, xx_T, best_idx,
                                      present);
  cross_partial<<<nS * SPLIT_S, 256, 0, stream>>>(preds_S, preds_T, gt_inds_S,
                                                  best_idx, present, acc_S);
  student_final<<<1, 128, 0, stream>>>(acc_S, xx_T, gt_inds_S, best_idx,
                                       present, out, nS);
}

// Round 4
// 70.429 us; speedup vs baseline: 1.2427x; 1.0083x over previous
//
#include <hip/hip_runtime.h>
#include <math.h>

#define NPIX 65536          // 256*256 pixels per instance
#define NGROUPS 64
#define DICE_EPS 1e-5f
#define SPLIT_T 8           // teacher: 256*8  = 2048 blocks, 8 KB f32/stream each
#define SPLIT_SSELF 16      // student self: 128*16 = 2048 (same blocks, folded)
#define SPLIT_S 16          // cross phase blocks per student
#define MAX_NT 256

__device__ __forceinline__ void dice3(const float4& a, const float4& b,
                                      float& inter, float& xx, float& tt) {
  inter += a.x * b.x + a.y * b.y + a.z * b.z + a.w * b.w;
  xx    += a.x * a.x + a.y * a.y + a.z * a.z + a.w * a.w;
  tt    += b.x * b.x + b.y * b.y + b.z * b.z + b.w * b.w;
}
__device__ __forceinline__ float dot4(const float4& a) {
  return a.x * a.x + a.y * a.y + a.z * a.z + a.w * a.w;
}

// ---------------------------------------------------------------------------
// Kernel 1: fused streaming phase, 2048 blocks, each block does
//   (a) teacher instance i=b/8, chunk c=b%8: inter/xx/tt over 2048 float4/stream
//       with an explicit cur/next software pipeline (named regs, static idx)
//   (b) student instance s=b/16, chunk cs=b%16: sum(s*s) over 1024 float4
// Longer block lifetime + >=8 loads in flight per wave for latency hiding.
// ---------------------------------------------------------------------------
__global__ __launch_bounds__(256) void stream_partials(
    const float* __restrict__ preds_T, const float* __restrict__ gt_T,
    const float* __restrict__ preds_S, int nS,
    float* __restrict__ acc_T, float* __restrict__ acc_S) {
  const int tid = threadIdx.x;
  const int b = blockIdx.x;

  // ---- (a) teacher segment: 2048 float4 per stream, 8 per thread ----
  const int i = b / SPLIT_T;
  const int c = b % SPLIT_T;
  const size_t tb = (size_t)i * NPIX + (size_t)c * (NPIX / SPLIT_T);
  const float4* __restrict__ x = (const float4*)(preds_T + tb);
  const float4* __restrict__ t = (const float4*)(gt_T + tb);

  float inter = 0.f, xx = 0.f, tt = 0.f;
  // prologue: batch 0 (2 f4 per stream)
  float4 ca0 = x[tid], ca1 = x[tid + 256];
  float4 cb0 = t[tid], cb1 = t[tid + 256];
#pragma unroll
  for (int k = 2; k < 8; k += 2) {
    // issue next batch before consuming current (keeps ~8 loads in flight)
    float4 na0 = x[tid + k * 256], na1 = x[tid + (k + 1) * 256];
    float4 nb0 = t[tid + k * 256], nb1 = t[tid + (k + 1) * 256];
    dice3(ca0, cb0, inter, xx, tt);
    dice3(ca1, cb1, inter, xx, tt);
    ca0 = na0; ca1 = na1; cb0 = nb0; cb1 = nb1;
  }
  dice3(ca0, cb0, inter, xx, tt);
  dice3(ca1, cb1, inter, xx, tt);

  // ---- (b) student self-dot segment: 1024 float4, 4 per thread ----
  const int s = b / SPLIT_SSELF;
  const int cs = b % SPLIT_SSELF;
  float sxx = 0.f;
  if (s < nS) {
    const size_t sb = (size_t)s * NPIX + (size_t)cs * (NPIX / SPLIT_SSELF);
    const float4* __restrict__ xs = (const float4*)(preds_S + sb);
    float4 s0 = xs[tid], s1 = xs[tid + 256];
    float4 s2 = xs[tid + 512], s3 = xs[tid + 768];
    sxx = dot4(s0) + dot4(s1) + dot4(s2) + dot4(s3);
  }

  // ---- reductions: 4 values, wave shuffle then LDS ----
  for (int off = 32; off > 0; off >>= 1) {
    inter += __shfl_down(inter, off);
    xx    += __shfl_down(xx, off);
    tt    += __shfl_down(tt, off);
    sxx   += __shfl_down(sxx, off);
  }
  __shared__ float sm[4][4];
  const int wave = tid >> 6, lane = tid & 63;
  if (lane == 0) {
    sm[0][wave] = inter; sm[1][wave] = xx; sm[2][wave] = tt; sm[3][wave] = sxx;
  }
  __syncthreads();
  if (tid == 0) {
    float I = 0.f, X = 0.f, T = 0.f, SX = 0.f;
    for (int w = 0; w < 4; ++w) {
      I += sm[0][w]; X += sm[1][w]; T += sm[2][w]; SX += sm[3][w];
    }
    atomicAdd(&acc_T[i * 3 + 0], I);
    atomicAdd(&acc_T[i * 3 + 1], X);
    atomicAdd(&acc_T[i * 3 + 2], T);
    if (s < nS) atomicAdd(&acc_S[s * 2 + 1], SX);
  }
}

// ---------------------------------------------------------------------------
// Kernel 2: finalize teacher dice + per-group argmin (first-min semantics,
// matching jnp.argmin). One block; gt_inds_T staged in LDS.
// ---------------------------------------------------------------------------
__global__ __launch_bounds__(256) void finalize_nms(
    const float* __restrict__ acc_T, const int* __restrict__ gt_inds_T, int nT,
    float* __restrict__ xx_T, int* __restrict__ best_idx,
    int* __restrict__ present) {
  __shared__ float iou[MAX_NT];
  __shared__ int ginds[MAX_NT];
  const int i = threadIdx.x;
  if (i < nT) {
    float I = acc_T[i * 3 + 0], X = acc_T[i * 3 + 1], T = acc_T[i * 3 + 2];
    iou[i] = 1.f - 2.f * I / (X + T + DICE_EPS);
    ginds[i] = gt_inds_T[i];
    xx_T[i] = X;
  }
  __syncthreads();
  if (i < NGROUPS) {
    float bv = INFINITY;
    int bi = 0, pres = 0;
    for (int k = 0; k < nT; ++k) {
      if (ginds[k] == i) {
        pres = 1;
        float v = iou[k];
        if (v < bv) { bv = v; bi = k; }   // strict < keeps FIRST min index
      }
    }
    best_idx[i] = bi;
    present[i] = pres;
  }
}

// ---------------------------------------------------------------------------
// Kernel 3: cross terms — per student, sum s * matched_t, pipelined.
// Mostly L2/L3-resident reads after kernel 1. Grid = nS*SPLIT_S blocks.
// ---------------------------------------------------------------------------
__global__ __launch_bounds__(256) void cross_partial(
    const float* __restrict__ preds_S, const float* __restrict__ preds_T,
    const int* __restrict__ gt_inds_S, const int* __restrict__ best_idx,
    const int* __restrict__ present, float* __restrict__ acc_S) {
  const int s = blockIdx.x / SPLIT_S;
  const int c = blockIdx.x % SPLIT_S;
  const int g = gt_inds_S[s];
  if (!present[g]) return;
  const int j = best_idx[g];

  const size_t off_s = (size_t)s * NPIX + (size_t)c * (NPIX / SPLIT_S);
  const size_t off_t = (size_t)j * NPIX + (size_t)c * (NPIX / SPLIT_S);
  const float4* __restrict__ x = (const float4*)(preds_S + off_s);
  const float4* __restrict__ t = (const float4*)(preds_T + off_t);

  const int tid = threadIdx.x;
  float inter = 0.f;
  // 1024 float4 per stream per block -> 4 per thread; all 8 loads hoisted
  float4 a0 = x[tid], a1 = x[tid + 256], a2 = x[tid + 512], a3 = x[tid + 768];
  float4 b0 = t[tid], b1 = t[tid + 256], b2 = t[tid + 512], b3 = t[tid + 768];
  inter += a0.x * b0.x + a0.y * b0.y + a0.z * b0.z + a0.w * b0.w;
  inter += a1.x * b1.x + a1.y * b1.y + a1.z * b1.z + a1.w * b1.w;
  inter += a2.x * b2.x + a2.y * b2.y + a2.z * b2.z + a2.w * b2.w;
  inter += a3.x * b3.x + a3.y * b3.y + a3.z * b3.z + a3.w * b3.w;

  for (int off = 32; off > 0; off >>= 1) inter += __shfl_down(inter, off);
  __shared__ float sm[4];
  if ((tid & 63) == 0) sm[tid >> 6] = inter;
  __syncthreads();
  if (tid == 0) {
    float I = sm[0] + sm[1] + sm[2] + sm[3];
    atomicAdd(&acc_S[s * 2 + 0], I);
  }
}

// ---------------------------------------------------------------------------
// Kernel 4: final masked sum over students -> scalar (direct write).
// ---------------------------------------------------------------------------
__global__ __launch_bounds__(128) void student_final(
    const float* __restrict__ acc_S, const float* __restrict__ xx_T,
    const int* __restrict__ gt_inds_S, const int* __restrict__ best_idx,
    const int* __restrict__ present, float* __restrict__ out, int nS) {
  float v = 0.f;
  const int s = threadIdx.x;   // 128 threads, one per student
  if (s < nS) {
    const int g = gt_inds_S[s];
    if (present[g]) {
      const int j = best_idx[g];
      float I = acc_S[s * 2 + 0], X = acc_S[s * 2 + 1];
      v = 1.f - 2.f * I / (X + xx_T[j] + DICE_EPS);
    }
  }
  for (int off = 32; off > 0; off >>= 1) v += __shfl_down(v, off);
  __shared__ float p[2];
  if ((threadIdx.x & 63) == 0) p[threadIdx.x >> 6] = v;
  __syncthreads();
  if (threadIdx.x == 0) *out = p[0] + p[1];
}

extern "C" void kernel_launch(void* const* d_in, const int* in_sizes, int n_in,
                              void* d_out, int out_size, void* d_ws, size_t ws_size,
                              hipStream_t stream) {
  const float* preds_T = (const float*)d_in[0];
  const float* preds_S = (const float*)d_in[1];
  const float* gt_T    = (const float*)d_in[3];
  // d_in[2]=im_ind, d_in[4]=gt_S, d_in[5]=iter: unused by the reference
  const int* gt_inds_T = (const int*)d_in[6];
  const int* gt_inds_S = (const int*)d_in[7];
  float* out = (float*)d_out;

  const int nT = in_sizes[6];   // 256
  const int nS = in_sizes[7];   // 128

  // workspace layout (floats): acc_T[nT*3] | acc_S[nS*2] | xx_T[nT] | ints
  float* acc_T    = (float*)d_ws;
  float* acc_S    = acc_T + (size_t)nT * 3;
  float* xx_T     = acc_S + (size_t)nS * 2;
  int*   best_idx = (int*)(xx_T + nT);
  int*   present  = best_idx + NGROUPS;

  hipMemsetAsync(d_ws, 0, ((size_t)nT * 3 + (size_t)nS * 2) * sizeof(float),
                 stream);

  stream_partials<<<nT * SPLIT_T, 256, 0, stream>>>(preds_T, gt_T, preds_S, nS,
                                                    acc_T, acc_S);
  finalize_nms<<<1, 256, 0, stream>>>(acc_T, gt_inds_T, nT, xx_T, best_idx,
                                      present);
  cross_partial<<<nS * SPLIT_S, 256, 0, stream>>>(preds_S, preds_T, gt_inds_S,
                                                  best_idx, present, acc_S);
  student_final<<<1, 128, 0, stream>>>(acc_S, xx_T, gt_inds_S, best_idx,
                                       present, out, nS);
}